// Round 4
// baseline (43154.065 us; speedup 1.0000x reference)
//
#include <hip/hip_runtime.h>

typedef unsigned long long u64;

#define BB 16
#define TT 1500
#define NG3 1536
#define GM (BB * TT)   /* 24000 */
#define GK 512
#define LNEPS 1e-5f
#define RWG0 96
#define RWG1 96
#define CPW 16
#define PROGSTRIDE 64  /* uints -> 256B per progress flag line */
#define HRING 8

// ---------------- helpers ----------------
__device__ __forceinline__ float sigmoidf_(float x) { return 1.f / (1.f + __expf(-x)); }
__device__ __forceinline__ float tanhf_(float x) {
  x = fminf(15.f, fmaxf(-15.f, x));
  float e = __expf(2.f * x);
  return (e - 1.f) / (e + 1.f);
}
__device__ __forceinline__ float red16_(float v) {
  v += __shfl_xor(v, 1, 64);
  v += __shfl_xor(v, 2, 64);
  v += __shfl_xor(v, 4, 64);
  v += __shfl_xor(v, 8, 64);
  return v;
}
// XOR-swizzled physical float4-chunk index for a [512]-float LDS row
__device__ __forceinline__ int physc(int lc) { return (lc & ~7) | ((lc ^ (lc >> 3)) & 7); }

__device__ __forceinline__ u64 ldA(const u64* p) {
  return __hip_atomic_load(p, __ATOMIC_RELAXED, __HIP_MEMORY_SCOPE_AGENT);
}
__device__ __forceinline__ void stA(u64* p, u64 v) {
  __hip_atomic_store(p, v, __ATOMIC_RELAXED, __HIP_MEMORY_SCOPE_AGENT);
}
__device__ __forceinline__ unsigned ldA32(const unsigned* p) {
  return __hip_atomic_load(p, __ATOMIC_RELAXED, __HIP_MEMORY_SCOPE_AGENT);
}
__device__ __forceinline__ void stA32(unsigned* p, unsigned v) {
  __hip_atomic_store(p, v, __ATOMIC_RELAXED, __HIP_MEMORY_SCOPE_AGENT);
}
__device__ __forceinline__ u64 pk(unsigned tag, float v) {
  return ((u64)tag << 32) | (u64)__float_as_uint(v);
}

// Batched tagged poll: 32 u64 at base[l16*4 + i*64 + q]; spin until ALL tags == want.
__device__ __forceinline__ void poll32(const u64* __restrict__ base, int l16, unsigned want,
                                       float* dst) {
  const u64* p = base + l16 * 4;
  for (;;) {
    unsigned bad = 0;
#pragma unroll
    for (int i = 0; i < 8; ++i) {
      u64 a = ldA(p + i * 64 + 0);
      u64 b = ldA(p + i * 64 + 1);
      u64 c = ldA(p + i * 64 + 2);
      u64 d = ldA(p + i * 64 + 3);
      dst[i * 4 + 0] = __uint_as_float((unsigned)a);
      dst[i * 4 + 1] = __uint_as_float((unsigned)b);
      dst[i * 4 + 2] = __uint_as_float((unsigned)c);
      dst[i * 4 + 3] = __uint_as_float((unsigned)d);
      bad |= ((unsigned)(a >> 32) ^ want) | ((unsigned)(b >> 32) ^ want) |
             ((unsigned)(c >> 32) ^ want) | ((unsigned)(d >> 32) ^ want);
    }
    if (!bad) return;
    __builtin_amdgcn_s_sleep(2);
  }
}

// ---------------- big GEMM: C[M,N] = A[M,K] @ W[N,K]^T (fp32) ----------------
__global__ __launch_bounds__(256) void gemm_nt(const float* __restrict__ A,
                                               const float* __restrict__ W,
                                               float* __restrict__ C) {
  __shared__ __align__(16) float As[32][68];
  __shared__ __align__(16) float Ws[32][68];
  const int m0 = blockIdx.x * 64;
  const int n0 = blockIdx.y * 64;
  const int tid = threadIdx.x;
  const int tm = tid & 15, tn = tid >> 4;
  float acc[4][4] = {};
  for (int k0 = 0; k0 < GK; k0 += 32) {
#pragma unroll
    for (int u = 0; u < 2; ++u) {
      int idx = tid + u * 256;
      int r = idx >> 3;
      int kq = (idx & 7) * 4;
      float4 a = *reinterpret_cast<const float4*>(&A[(size_t)(m0 + r) * GK + k0 + kq]);
      As[kq + 0][r] = a.x; As[kq + 1][r] = a.y; As[kq + 2][r] = a.z; As[kq + 3][r] = a.w;
      float4 w = *reinterpret_cast<const float4*>(&W[(size_t)(n0 + r) * GK + k0 + kq]);
      Ws[kq + 0][r] = w.x; Ws[kq + 1][r] = w.y; Ws[kq + 2][r] = w.z; Ws[kq + 3][r] = w.w;
    }
    __syncthreads();
#pragma unroll
    for (int kk = 0; kk < 32; ++kk) {
      float a[4], w[4];
      *reinterpret_cast<float4*>(a) = *reinterpret_cast<const float4*>(&As[kk][tm * 4]);
      *reinterpret_cast<float4*>(w) = *reinterpret_cast<const float4*>(&Ws[kk][tn * 4]);
#pragma unroll
      for (int i = 0; i < 4; ++i)
#pragma unroll
        for (int q = 0; q < 4; ++q)
          acc[i][q] = fmaf(a[i], w[q], acc[i][q]);
    }
    __syncthreads();
  }
#pragma unroll
  for (int i = 0; i < 4; ++i) {
    float4 v = make_float4(acc[i][0], acc[i][1], acc[i][2], acc[i][3]);
    *reinterpret_cast<float4*>(&C[(size_t)(m0 + tm * 4 + i) * NG3 + n0 + tn * 4]) = v;
  }
}

// ---------------- fused 2-layer persistent GRU scan, barrier-free (tagged data) ----
// WGs 0..95: layer 0 (cols = wg*16..+16). WGs 96..191: layer 1.
// G0: u64[2][16][1536]; G1: u64[2][16][2048] (cols 1536..2048 = x_n part);
// Hb: u64[8][16][512] h0 broadcast ring; prog: layer-1 progress flags.
__global__ __launch_bounds__(256, 1) void gru_fused(
    const float* __restrict__ Wh0, const float* __restrict__ Wi1,
    const float* __restrict__ Wh1, const float* __restrict__ X0,
    const float* __restrict__ lnw, const float* __restrict__ lnb,
    float* __restrict__ out, u64* __restrict__ G0, u64* __restrict__ G1,
    u64* __restrict__ Hb, unsigned* __restrict__ prog) {
  __shared__ __align__(16) float shA[BB][512];  // h of this layer (swizzled chunks)
  __shared__ __align__(16) float shB[BB][512];  // layer 1 only: h0(t) copy

  const int tid = threadIdx.x;
  const int wg = blockIdx.x;
  const int lane = tid & 63;
  const int wv = tid >> 6;
  const int ks = lane & 15;      // phase-1: K-chunk (32 floats) AND producer batch row
  const int cq = lane >> 4;      // phase-1: col within wave
  const int b2 = wv * 4 + (lane >> 4);  // phase-2: batch row
  const int l16 = lane & 15;

  // zero h
  for (int idx = tid; idx < BB * 512; idx += 256) (&shA[0][0])[idx] = 0.f;

  if (wg < RWG0) {
    // ================= LAYER 0 =================
    const int col = wg * CPW + wv * 4 + cq;
    float wreg[32];
#pragma unroll
    for (int q = 0; q < 8; ++q)
      *reinterpret_cast<float4*>(&wreg[q * 4]) =
          *reinterpret_cast<const float4*>(&Wh0[(size_t)col * 512 + ks * 32 + q * 4]);
    __syncthreads();

    for (int t = 0; t < TT; ++t) {
      // writers throttle on layer-1 progress (ring depth HRING)
      if (wg < BB && t >= HRING) {
        if (tid < RWG1) {
          while (ldA32(&prog[(size_t)tid * PROGSTRIDE]) < (unsigned)(t - (HRING - 1)))
            __builtin_amdgcn_s_sleep(2);
        }
        __syncthreads();
      }
      // early prefetch (plain cached loads, immutable X0)
      float xv = (col < 1024) ? X0[((size_t)ks * TT + t) * NG3 + col] : 0.f;
      float xn[32];
#pragma unroll
      for (int i = 0; i < 8; ++i)
        *reinterpret_cast<float4*>(&xn[i * 4]) = *reinterpret_cast<const float4*>(
            &X0[((size_t)b2 * TT + t) * NG3 + 1024 + l16 * 4 + i * 64]);

      // ---- phase 1: h-gates for our 16 cols ----
      float gout = 0.f;
#pragma unroll 2
      for (int b = 0; b < 16; ++b) {
        const float* hrow = &shA[b][0];
        float p = 0.f;
#pragma unroll
        for (int i = 0; i < 8; ++i) {
          float hv[4];
          *reinterpret_cast<float4*>(hv) =
              *reinterpret_cast<const float4*>(&hrow[(((ks << 3) | ((i ^ ks) & 7)) << 2)]);
          p = fmaf(hv[0], wreg[i * 4 + 0], p);
          p = fmaf(hv[1], wreg[i * 4 + 1], p);
          p = fmaf(hv[2], wreg[i * 4 + 2], p);
          p = fmaf(hv[3], wreg[i * 4 + 3], p);
        }
        p = red16_(p);
        if (ks == b) gout = p;
      }
      stA(&G0[(size_t)(t & 1) * (BB * NG3) + (size_t)ks * NG3 + col], pk(t + 1, gout + xv));

      // ---- phase 2 (redundant, all b) ----
      const u64* Grow = G0 + (size_t)(t & 1) * (BB * NG3) + (size_t)b2 * NG3;
      float gr[32], gz[32], np_[32];
      float s = 0.f, s2 = 0.f;
      poll32(Grow, l16, t + 1, gr);
#pragma unroll
      for (int k = 0; k < 32; ++k) { s += gr[k]; s2 += gr[k] * gr[k]; }
      s = red16_(s); s2 = red16_(s2);
      const float mr = s * (1.f / 512.f);
      const float rsr = rsqrtf(s2 * (1.f / 512.f) - mr * mr + LNEPS);

      float gn[32];
      poll32(Grow + 1024, l16, t + 1, gn);
      s = 0.f; s2 = 0.f;
#pragma unroll
      for (int i = 0; i < 8; ++i)
#pragma unroll
        for (int q = 0; q < 4; ++q) {
          int k = i * 4 + q, j2 = l16 * 4 + i * 64 + q;
          float rv = sigmoidf_((gr[k] - mr) * rsr * lnw[j2] + lnb[j2]);
          float v = xn[k] + rv * gn[k];
          np_[k] = v; s += v; s2 += v * v;
        }
      s = red16_(s); s2 = red16_(s2);
      const float mn = s * (1.f / 512.f);
      const float rsn = rsqrtf(s2 * (1.f / 512.f) - mn * mn + LNEPS);

      poll32(Grow + 512, l16, t + 1, gz);
      s = 0.f; s2 = 0.f;
#pragma unroll
      for (int k = 0; k < 32; ++k) { s += gz[k]; s2 += gz[k] * gz[k]; }
      s = red16_(s); s2 = red16_(s2);
      const float mz = s * (1.f / 512.f);
      const float rsz = rsqrtf(s2 * (1.f / 512.f) - mz * mz + LNEPS);

#pragma unroll
      for (int i = 0; i < 8; ++i) {
        int j2 = l16 * 4 + i * 64;
        int off = physc(l16 + i * 16) << 2;
        float hold[4], hv[4];
        *reinterpret_cast<float4*>(hold) = *reinterpret_cast<const float4*>(&shA[b2][off]);
#pragma unroll
        for (int q = 0; q < 4; ++q) {
          int k = i * 4 + q;
          float z = sigmoidf_((gz[k] - mz) * rsz * lnw[512 + j2 + q] + lnb[512 + j2 + q]);
          float n = tanhf_((np_[k] - mn) * rsn * lnw[1024 + j2 + q] + lnb[1024 + j2 + q]);
          hv[q] = (1.f - z) * n + z * hold[q];
        }
        *reinterpret_cast<float4*>(&shA[b2][off]) = *reinterpret_cast<const float4*>(hv);
        if (wg == b2) {  // broadcast h0(t) row b2
          u64* Hw = Hb + (size_t)(t & 7) * (BB * 512) + (size_t)b2 * 512 + j2;
#pragma unroll
          for (int q = 0; q < 4; ++q) stA(&Hw[q], pk(t + 1, hv[q]));
        }
      }
      __syncthreads();
    }
  } else {
    // ================= LAYER 1 =================
    const int wg1 = wg - RWG0;
    const int col = wg1 * CPW + wv * 4 + cq;
    const float* lnw1 = lnw + 3 * 512;
    const float* lnb1 = lnb + 3 * 512;
    float wi[32], wh[32];
#pragma unroll
    for (int q = 0; q < 8; ++q) {
      *reinterpret_cast<float4*>(&wi[q * 4]) =
          *reinterpret_cast<const float4*>(&Wi1[(size_t)col * 512 + ks * 32 + q * 4]);
      *reinterpret_cast<float4*>(&wh[q * 4]) =
          *reinterpret_cast<const float4*>(&Wh1[(size_t)col * 512 + ks * 32 + q * 4]);
    }
    __syncthreads();

    for (int t = 0; t < TT; ++t) {
      // ---- copy h0(t) ring slot -> shB ----
      const u64* Hrow = Hb + (size_t)(t & 7) * (BB * 512) + (size_t)b2 * 512;
      float h0v[32];
      poll32(Hrow, l16, t + 1, h0v);
#pragma unroll
      for (int i = 0; i < 8; ++i)
        *reinterpret_cast<float4*>(&shB[b2][physc(l16 + i * 16) << 2]) =
            *reinterpret_cast<const float4*>(&h0v[i * 4]);
      __syncthreads();
      if (tid == 0) stA32(&prog[(size_t)wg1 * PROGSTRIDE], (unsigned)(t + 1));

      // ---- phase 1: two matvecs (Wi1·h0 and Wh1·h1) ----
      float px = 0.f, ph = 0.f;
#pragma unroll 2
      for (int b = 0; b < 16; ++b) {
        const float* h0row = &shB[b][0];
        const float* h1row = &shA[b][0];
        float pxx = 0.f, phh = 0.f;
#pragma unroll
        for (int i = 0; i < 8; ++i) {
          int chunk = ((ks << 3) | ((i ^ ks) & 7)) << 2;
          float a[4], c[4];
          *reinterpret_cast<float4*>(a) = *reinterpret_cast<const float4*>(&h0row[chunk]);
          *reinterpret_cast<float4*>(c) = *reinterpret_cast<const float4*>(&h1row[chunk]);
#pragma unroll
          for (int q = 0; q < 4; ++q) {
            pxx = fmaf(a[q], wi[i * 4 + q], pxx);
            phh = fmaf(c[q], wh[i * 4 + q], phh);
          }
        }
        pxx = red16_(pxx); phh = red16_(phh);
        if (ks == b) { px = pxx; ph = phh; }
      }
      u64* Gw = G1 + (size_t)(t & 1) * (BB * 2048) + (size_t)ks * 2048;
      if (col < 1024) {
        stA(&Gw[col], pk(t + 1, px + ph));
      } else {
        stA(&Gw[col], pk(t + 1, ph));        // h_n
        stA(&Gw[col + 512], pk(t + 1, px));  // x_n
      }

      // ---- phase 2 ----
      const u64* Grow = G1 + (size_t)(t & 1) * (BB * 2048) + (size_t)b2 * 2048;
      float gr[32], gz[32], np_[32];
      float s = 0.f, s2 = 0.f;
      poll32(Grow, l16, t + 1, gr);
#pragma unroll
      for (int k = 0; k < 32; ++k) { s += gr[k]; s2 += gr[k] * gr[k]; }
      s = red16_(s); s2 = red16_(s2);
      const float mr = s * (1.f / 512.f);
      const float rsr = rsqrtf(s2 * (1.f / 512.f) - mr * mr + LNEPS);

      float gn[32], xn[32];
      poll32(Grow + 1024, l16, t + 1, gn);
      poll32(Grow + 1536, l16, t + 1, xn);
      s = 0.f; s2 = 0.f;
#pragma unroll
      for (int i = 0; i < 8; ++i)
#pragma unroll
        for (int q = 0; q < 4; ++q) {
          int k = i * 4 + q, j2 = l16 * 4 + i * 64 + q;
          float rv = sigmoidf_((gr[k] - mr) * rsr * lnw1[j2] + lnb1[j2]);
          float v = xn[k] + rv * gn[k];
          np_[k] = v; s += v; s2 += v * v;
        }
      s = red16_(s); s2 = red16_(s2);
      const float mn = s * (1.f / 512.f);
      const float rsn = rsqrtf(s2 * (1.f / 512.f) - mn * mn + LNEPS);

      poll32(Grow + 512, l16, t + 1, gz);
      s = 0.f; s2 = 0.f;
#pragma unroll
      for (int k = 0; k < 32; ++k) { s += gz[k]; s2 += gz[k] * gz[k]; }
      s = red16_(s); s2 = red16_(s2);
      const float mz = s * (1.f / 512.f);
      const float rsz = rsqrtf(s2 * (1.f / 512.f) - mz * mz + LNEPS);

#pragma unroll
      for (int i = 0; i < 8; ++i) {
        int j2 = l16 * 4 + i * 64;
        int off = physc(l16 + i * 16) << 2;
        float hold[4], res[4], hv[4];
        *reinterpret_cast<float4*>(hold) = *reinterpret_cast<const float4*>(&shA[b2][off]);
        *reinterpret_cast<float4*>(res) = *reinterpret_cast<const float4*>(&shB[b2][off]);
#pragma unroll
        for (int q = 0; q < 4; ++q) {
          int k = i * 4 + q;
          float z = sigmoidf_((gz[k] - mz) * rsz * lnw1[512 + j2 + q] + lnb1[512 + j2 + q]);
          float n = tanhf_((np_[k] - mn) * rsn * lnw1[1024 + j2 + q] + lnb1[1024 + j2 + q]);
          hv[q] = (1.f - z) * n + z * hold[q] + res[q];
        }
        *reinterpret_cast<float4*>(&shA[b2][off]) = *reinterpret_cast<const float4*>(hv);
        if (wg1 == b2) {
          *reinterpret_cast<float4*>(&out[((size_t)b2 * TT + t) * 512 + j2]) =
              *reinterpret_cast<const float4*>(hv);
        }
      }
      __syncthreads();
    }
  }
}

// ---------------- launch ----------------
extern "C" void kernel_launch(void* const* d_in, const int* in_sizes, int n_in,
                              void* d_out, int out_size, void* d_ws, size_t ws_size,
                              hipStream_t stream) {
  (void)in_sizes; (void)n_in; (void)out_size; (void)ws_size;
  const float* x   = (const float*)d_in[0];
  const float* Wi  = (const float*)d_in[1];  // [2][1536][512]
  const float* Wh  = (const float*)d_in[2];  // [2][1536][512]
  const float* lnw = (const float*)d_in[3];  // [2][3][512]
  const float* lnb = (const float*)d_in[4];
  float* out = (float*)d_out;

  float* X0 = (float*)d_ws;                           // [24000][1536] f32
  u64* G0 = (u64*)(X0 + (size_t)GM * NG3);            // [2][16][1536]
  u64* G1 = G0 + 2 * BB * NG3;                        // [2][16][2048]
  u64* Hb = G1 + 2 * BB * 2048;                       // [8][16][512]
  unsigned* prog = (unsigned*)(Hb + HRING * BB * 512);// [96][64]

  size_t clear_bytes = (size_t)(2 * BB * NG3 + 2 * BB * 2048 + HRING * BB * 512) * 8 +
                       (size_t)RWG1 * PROGSTRIDE * 4;
  hipMemsetAsync(G0, 0, clear_bytes, stream);

  dim3 ggrid(GM / 64, NG3 / 64);
  gemm_nt<<<ggrid, 256, 0, stream>>>(x, Wi, X0);  // layer-0 input gates
  gru_fused<<<RWG0 + RWG1, 256, 0, stream>>>(
      Wh, Wi + (size_t)NG3 * 512, Wh + (size_t)NG3 * 512, X0, lnw, lnb, out,
      G0, G1, Hb, prog);
}

// Round 5
// 33159.900 us; speedup vs baseline: 1.3014x; 1.3014x over previous
//
#include <hip/hip_runtime.h>

typedef unsigned long long u64;

#define BB 16
#define TT 1500
#define NG3 1536
#define GM (BB * TT)   /* 24000 */
#define GK 512
#define LNEPS 1e-5f
#define NCW 96         /* compute WGs per layer */
#define FL 64          /* flag line stride in uints (256B) */

// ---------------- helpers ----------------
__device__ __forceinline__ float sigmoidf_(float x) { return 1.f / (1.f + __expf(-x)); }
__device__ __forceinline__ float tanhf_(float x) {
  x = fminf(15.f, fmaxf(-15.f, x));
  float e = __expf(2.f * x);
  return (e - 1.f) / (e + 1.f);
}
__device__ __forceinline__ float red16_(float v) {
  v += __shfl_xor(v, 1, 64); v += __shfl_xor(v, 2, 64);
  v += __shfl_xor(v, 4, 64); v += __shfl_xor(v, 8, 64);
  return v;
}
__device__ __forceinline__ float red64_(float v) {
  v += __shfl_xor(v, 1, 64);  v += __shfl_xor(v, 2, 64);
  v += __shfl_xor(v, 4, 64);  v += __shfl_xor(v, 8, 64);
  v += __shfl_xor(v, 16, 64); v += __shfl_xor(v, 32, 64);
  return v;
}
// XOR-swizzled physical float4-chunk index for a [512]-float LDS row
__device__ __forceinline__ int physc(int lc) { return (lc & ~7) | ((lc ^ (lc >> 3)) & 7); }

__device__ __forceinline__ u64 ldA(const u64* p) {
  return __hip_atomic_load(p, __ATOMIC_RELAXED, __HIP_MEMORY_SCOPE_AGENT);
}
__device__ __forceinline__ void stA8(u64* p, u64 v) {
  __hip_atomic_store(p, v, __ATOMIC_RELAXED, __HIP_MEMORY_SCOPE_AGENT);
}
__device__ __forceinline__ void stAf(float* p, float v) {
  __hip_atomic_store(p, v, __ATOMIC_RELAXED, __HIP_MEMORY_SCOPE_AGENT);
}
__device__ __forceinline__ unsigned ldA32(const unsigned* p) {
  return __hip_atomic_load(p, __ATOMIC_RELAXED, __HIP_MEMORY_SCOPE_AGENT);
}
__device__ __forceinline__ void stA32(unsigned* p, unsigned v) {
  __hip_atomic_store(p, v, __ATOMIC_RELAXED, __HIP_MEMORY_SCOPE_AGENT);
}

// ---------------- big GEMM: C[M,N] = A[M,K] @ W[N,K]^T (fp32) ----------------
__global__ __launch_bounds__(256) void gemm_nt(const float* __restrict__ A,
                                               const float* __restrict__ W,
                                               float* __restrict__ C) {
  __shared__ __align__(16) float As[32][68];
  __shared__ __align__(16) float Ws[32][68];
  const int m0 = blockIdx.x * 64;
  const int n0 = blockIdx.y * 64;
  const int tid = threadIdx.x;
  const int tm = tid & 15, tn = tid >> 4;
  float acc[4][4] = {};
  for (int k0 = 0; k0 < GK; k0 += 32) {
#pragma unroll
    for (int u = 0; u < 2; ++u) {
      int idx = tid + u * 256;
      int r = idx >> 3;
      int kq = (idx & 7) * 4;
      float4 a = *reinterpret_cast<const float4*>(&A[(size_t)(m0 + r) * GK + k0 + kq]);
      As[kq + 0][r] = a.x; As[kq + 1][r] = a.y; As[kq + 2][r] = a.z; As[kq + 3][r] = a.w;
      float4 w = *reinterpret_cast<const float4*>(&W[(size_t)(n0 + r) * GK + k0 + kq]);
      Ws[kq + 0][r] = w.x; Ws[kq + 1][r] = w.y; Ws[kq + 2][r] = w.z; Ws[kq + 3][r] = w.w;
    }
    __syncthreads();
#pragma unroll
    for (int kk = 0; kk < 32; ++kk) {
      float a[4], w[4];
      *reinterpret_cast<float4*>(a) = *reinterpret_cast<const float4*>(&As[kk][tm * 4]);
      *reinterpret_cast<float4*>(w) = *reinterpret_cast<const float4*>(&Ws[kk][tn * 4]);
#pragma unroll
      for (int i = 0; i < 4; ++i)
#pragma unroll
        for (int q = 0; q < 4; ++q)
          acc[i][q] = fmaf(a[i], w[q], acc[i][q]);
    }
    __syncthreads();
  }
#pragma unroll
  for (int i = 0; i < 4; ++i) {
    float4 v = make_float4(acc[i][0], acc[i][1], acc[i][2], acc[i][3]);
    *reinterpret_cast<float4*>(&C[(size_t)(m0 + tm * 4 + i) * NG3 + n0 + tn * 4]) = v;
  }
}

// ---------------- fused 2-layer GRU scan ----------------
// WG 0..95   : layer-0 compute (16 cols each, weights in regs)
// WG 96..191 : layer-1 compute (16 cols, Wi1+Wh1 in regs, dual matvec)
// WG 192..207: layer-0 updater b = wg-192 (single wave)
// WG 208..223: layer-1 updater b = wg-208 (single wave)
// Protocol: data sc1-stores -> per-wave vmcnt(0) (+__syncthreads for multiwave)
// -> monotonic tag store. Consumers poll tags (relaxed agent) then read data.
__global__ __launch_bounds__(256, 1) void gru_fused(
    const float* __restrict__ Wh0, const float* __restrict__ Wi1,
    const float* __restrict__ Wh1, const float* __restrict__ X0,
    const float* __restrict__ lnw, const float* __restrict__ lnb,
    float* __restrict__ out, float* __restrict__ G0, float* __restrict__ G1,
    float* __restrict__ Hb0, float* __restrict__ Hb1, unsigned* __restrict__ tags) {
  unsigned* flags0 = tags;              // [96]
  unsigned* flags1 = tags + 96 * FL;    // [96]
  unsigned* h0tag  = tags + 192 * FL;   // [16]
  unsigned* h1tag  = tags + 208 * FL;   // [16]
  unsigned* prog1  = tags + 224 * FL;   // [112] (96 compute + 16 updater-1)

  __shared__ __align__(16) float shA[BB][512];
  __shared__ __align__(16) float shB[BB][512];

  const int tid = threadIdx.x, wg = blockIdx.x;
  const int lane = tid & 63, wv = tid >> 6;

  if (wg < 2 * NCW) {
    // ================= COMPUTE WGs =================
    const bool L1 = wg >= NCW;
    const int wgl = L1 ? wg - NCW : wg;
    const int ks = lane & 15, cq = lane >> 4;
    const int col = wgl * 16 + wv * 4 + cq;

    float wh[32], wi[32];
    {
      const float* Wp = (L1 ? Wh1 : Wh0) + (size_t)col * 512 + ks * 32;
#pragma unroll
      for (int q = 0; q < 8; ++q) *(float4*)&wh[q * 4] = *(const float4*)&Wp[q * 4];
      if (L1) {
        const float* Wq = Wi1 + (size_t)col * 512 + ks * 32;
#pragma unroll
        for (int q = 0; q < 8; ++q) *(float4*)&wi[q * 4] = *(const float4*)&Wq[q * 4];
      } else {
#pragma unroll
        for (int q = 0; q < 32; ++q) wi[q] = 0.f;
      }
    }
    for (int idx = tid; idx < BB * 512; idx += 256) (&shA[0][0])[idx] = 0.f;
    __syncthreads();

    const int rr = tid >> 4;         // copy: row
    const int cc = (tid & 15) * 32;  // copy: col base
    unsigned* selfflag = (L1 ? flags1 : flags0) + (size_t)wgl * FL;

    for (int t = 0; t < TT; ++t) {
      // ---- poll h tags ----
      if (t > 0 && tid < 16) {
        const unsigned* tg = (L1 ? h1tag : h0tag) + (size_t)tid * FL;
        while (ldA32(tg) < (unsigned)t) __builtin_amdgcn_s_sleep(1);
      }
      if (L1 && tid >= 16 && tid < 32) {
        const unsigned* tg = h0tag + (size_t)(tid - 16) * FL;
        while (ldA32(tg) < (unsigned)(t + 1)) __builtin_amdgcn_s_sleep(1);
      }
      __syncthreads();
      // ---- copy h rows into LDS (swizzled) ----
      if (t > 0) {
        const float* Hsrc = L1 ? (Hb1 + (size_t)((t - 1) & 1) * (BB * 512))
                               : (Hb0 + (size_t)((t - 1) & 7) * (BB * 512));
        const u64* src = (const u64*)(Hsrc + (size_t)rr * 512 + cc);
        float v[32];
#pragma unroll
        for (int i = 0; i < 16; ++i) {
          u64 w = ldA(src + i);
          v[2 * i] = __uint_as_float((unsigned)w);
          v[2 * i + 1] = __uint_as_float((unsigned)(w >> 32));
        }
#pragma unroll
        for (int j = 0; j < 8; ++j)
          *(float4*)&shA[rr][physc((cc >> 2) + j) << 2] = *(float4*)&v[j * 4];
      }
      if (L1) {
        const u64* src = (const u64*)(Hb0 + (size_t)(t & 7) * (BB * 512) + (size_t)rr * 512 + cc);
        float v[32];
#pragma unroll
        for (int i = 0; i < 16; ++i) {
          u64 w = ldA(src + i);
          v[2 * i] = __uint_as_float((unsigned)w);
          v[2 * i + 1] = __uint_as_float((unsigned)(w >> 32));
        }
#pragma unroll
        for (int j = 0; j < 8; ++j)
          *(float4*)&shB[rr][physc((cc >> 2) + j) << 2] = *(float4*)&v[j * 4];
      }
      __syncthreads();
      if (L1 && tid == 0) stA32(&prog1[(size_t)wgl * FL], (unsigned)(t + 1));

      // ---- matvec(s) ----
      float gh = 0.f, gx = 0.f;
#pragma unroll 2
      for (int b = 0; b < 16; ++b) {
        float p = 0.f, p2 = 0.f;
#pragma unroll
        for (int i = 0; i < 8; ++i) {
          const int off = ((ks << 3) | ((i ^ ks) & 7)) << 2;
          float hv[4];
          *(float4*)hv = *(const float4*)&shA[b][off];
          p = fmaf(hv[0], wh[i * 4 + 0], p);
          p = fmaf(hv[1], wh[i * 4 + 1], p);
          p = fmaf(hv[2], wh[i * 4 + 2], p);
          p = fmaf(hv[3], wh[i * 4 + 3], p);
          if (L1) {
            float bv[4];
            *(float4*)bv = *(const float4*)&shB[b][off];
            p2 = fmaf(bv[0], wi[i * 4 + 0], p2);
            p2 = fmaf(bv[1], wi[i * 4 + 1], p2);
            p2 = fmaf(bv[2], wi[i * 4 + 2], p2);
            p2 = fmaf(bv[3], wi[i * 4 + 3], p2);
          }
        }
        p = red16_(p);
        if (L1) p2 = red16_(p2);
        if (ks == b) { gh = p; gx = p2; }
      }
      // ---- store raw gate slice ----
      if (!L1) {
        stAf(&G0[(size_t)ks * NG3 + col], gh);
      } else {
        if (col < 1024) {
          stAf(&G1[(size_t)ks * 2048 + col], gh + gx);
        } else {
          stAf(&G1[(size_t)ks * 2048 + col], gh);        // h_n part
          stAf(&G1[(size_t)ks * 2048 + col + 512], gx);  // x_n part
        }
      }
      asm volatile("s_waitcnt vmcnt(0)" ::: "memory");
      __syncthreads();
      if (tid == 0) stA32(selfflag, (unsigned)(t + 1));
    }
  } else {
    // ================= UPDATER WGs (single wave) =================
    if (wv != 0) return;
    const bool L1u = wg >= 2 * NCW + 16;
    const int b = wg - (L1u ? 2 * NCW + 16 : 2 * NCW);
    const float* lnwL = lnw + (L1u ? 1536 : 0);
    const float* lnbL = lnb + (L1u ? 1536 : 0);
    const int j8 = lane * 8;
    float hold[8];
#pragma unroll
    for (int q = 0; q < 8; ++q) hold[q] = 0.f;

    for (int t = 0; t < TT; ++t) {
      // prefetch X0 row (layer 0 only; immutable, cached)
      float xr[8], xz[8], xnl[8];
      if (!L1u) {
        const float* Xr = X0 + ((size_t)b * TT + t) * NG3;
#pragma unroll
        for (int q = 0; q < 8; q += 4) {
          *(float4*)&xr[q]  = *(const float4*)&Xr[j8 + q];
          *(float4*)&xz[q]  = *(const float4*)&Xr[512 + j8 + q];
          *(float4*)&xnl[q] = *(const float4*)&Xr[1024 + j8 + q];
        }
      }
      // ---- poll 96 producer flags (+ h0 row tag for layer 1) ----
      {
        const unsigned* fl = L1u ? flags1 : flags0;
        const unsigned want = (unsigned)(t + 1);
        for (;;) {
          unsigned a = ldA32(&fl[(size_t)lane * FL]);
          unsigned c = (lane < 32) ? ldA32(&fl[(size_t)(64 + lane) * FL]) : want;
          unsigned d = (L1u && lane == 33) ? ldA32(&h0tag[(size_t)b * FL]) : want;
          if (__all(a >= want && c >= want && d >= want)) break;
          __builtin_amdgcn_s_sleep(1);
        }
      }
      // ---- read gate row (and h0 row for layer 1) ----
      float gr[8], gz[8], hn[8], xn[8], h0r[8];
      const float* Gr = L1u ? &G1[(size_t)b * 2048] : &G0[(size_t)b * NG3];
#pragma unroll
      for (int i = 0; i < 4; ++i) {
        u64 w;
        w = ldA((const u64*)&Gr[j8 + 2 * i]);
        gr[2 * i] = __uint_as_float((unsigned)w); gr[2 * i + 1] = __uint_as_float((unsigned)(w >> 32));
        w = ldA((const u64*)&Gr[512 + j8 + 2 * i]);
        gz[2 * i] = __uint_as_float((unsigned)w); gz[2 * i + 1] = __uint_as_float((unsigned)(w >> 32));
        w = ldA((const u64*)&Gr[1024 + j8 + 2 * i]);
        hn[2 * i] = __uint_as_float((unsigned)w); hn[2 * i + 1] = __uint_as_float((unsigned)(w >> 32));
      }
      if (L1u) {
#pragma unroll
        for (int i = 0; i < 4; ++i) {
          u64 w = ldA((const u64*)&Gr[1536 + j8 + 2 * i]);
          xn[2 * i] = __uint_as_float((unsigned)w); xn[2 * i + 1] = __uint_as_float((unsigned)(w >> 32));
        }
        const float* Hr = Hb0 + (size_t)(t & 7) * (BB * 512) + (size_t)b * 512;
#pragma unroll
        for (int i = 0; i < 4; ++i) {
          u64 w = ldA((const u64*)&Hr[j8 + 2 * i]);
          h0r[2 * i] = __uint_as_float((unsigned)w); h0r[2 * i + 1] = __uint_as_float((unsigned)(w >> 32));
        }
      } else {
#pragma unroll
        for (int q = 0; q < 8; ++q) { gr[q] += xr[q]; gz[q] += xz[q]; xn[q] = xnl[q]; }
      }
      // ---- LN + gates + h update (lane owns cols j8..j8+8) ----
      float s = 0.f, s2 = 0.f;
#pragma unroll
      for (int q = 0; q < 8; ++q) { s += gr[q]; s2 += gr[q] * gr[q]; }
      s = red64_(s); s2 = red64_(s2);
      float m = s * (1.f / 512.f);
      float rs = rsqrtf(s2 * (1.f / 512.f) - m * m + LNEPS);
      float rv[8];
#pragma unroll
      for (int q = 0; q < 8; ++q)
        rv[q] = sigmoidf_((gr[q] - m) * rs * lnwL[j8 + q] + lnbL[j8 + q]);

      s = 0.f; s2 = 0.f;
#pragma unroll
      for (int q = 0; q < 8; ++q) { s += gz[q]; s2 += gz[q] * gz[q]; }
      s = red64_(s); s2 = red64_(s2);
      m = s * (1.f / 512.f);
      rs = rsqrtf(s2 * (1.f / 512.f) - m * m + LNEPS);
      float zv[8];
#pragma unroll
      for (int q = 0; q < 8; ++q)
        zv[q] = sigmoidf_((gz[q] - m) * rs * lnwL[512 + j8 + q] + lnbL[512 + j8 + q]);

      float nv[8];
      s = 0.f; s2 = 0.f;
#pragma unroll
      for (int q = 0; q < 8; ++q) {
        nv[q] = xn[q] + rv[q] * hn[q];
        s += nv[q]; s2 += nv[q] * nv[q];
      }
      s = red64_(s); s2 = red64_(s2);
      m = s * (1.f / 512.f);
      rs = rsqrtf(s2 * (1.f / 512.f) - m * m + LNEPS);

      float h[8];
#pragma unroll
      for (int q = 0; q < 8; ++q) {
        float n = tanhf_((nv[q] - m) * rs * lnwL[1024 + j8 + q] + lnbL[1024 + j8 + q]);
        h[q] = (1.f - zv[q]) * n + zv[q] * hold[q];
        if (L1u) h[q] += h0r[q];
        hold[q] = h[q];
      }
      // ---- layer-0: throttle ring overwrite on layer-1 progress ----
      if (!L1u && t >= 8) {
        const unsigned want2 = (unsigned)(t - 7);
        for (;;) {
          unsigned a = ldA32(&prog1[(size_t)lane * FL]);
          unsigned c = (lane < 48) ? ldA32(&prog1[(size_t)(64 + lane) * FL]) : want2;
          if (__all(a >= want2 && c >= want2)) break;
          __builtin_amdgcn_s_sleep(2);
        }
      }
      // ---- broadcast h row (+ out for layer 1) ----
      {
        float* Hw = L1u ? (Hb1 + (size_t)(t & 1) * (BB * 512) + (size_t)b * 512)
                        : (Hb0 + (size_t)(t & 7) * (BB * 512) + (size_t)b * 512);
#pragma unroll
        for (int i = 0; i < 4; ++i) {
          u64 w = ((u64)__float_as_uint(h[2 * i + 1]) << 32) | (u64)__float_as_uint(h[2 * i]);
          stA8((u64*)&Hw[j8 + 2 * i], w);
        }
        if (L1u) {
          float* Or = out + ((size_t)b * TT + t) * 512 + j8;
          *(float4*)&Or[0] = *(float4*)&h[0];
          *(float4*)&Or[4] = *(float4*)&h[4];
        }
      }
      asm volatile("s_waitcnt vmcnt(0)" ::: "memory");
      if (L1u && lane == 0) stA32(&prog1[(size_t)(96 + b) * FL], (unsigned)(t + 1));
      if (lane == 0) stA32(&(L1u ? h1tag : h0tag)[(size_t)b * FL], (unsigned)(t + 1));
    }
  }
}

// ---------------- launch ----------------
extern "C" void kernel_launch(void* const* d_in, const int* in_sizes, int n_in,
                              void* d_out, int out_size, void* d_ws, size_t ws_size,
                              hipStream_t stream) {
  (void)in_sizes; (void)n_in; (void)out_size; (void)ws_size;
  const float* x   = (const float*)d_in[0];
  const float* Wi  = (const float*)d_in[1];  // [2][1536][512]
  const float* Wh  = (const float*)d_in[2];  // [2][1536][512]
  const float* lnw = (const float*)d_in[3];  // [2][3][512]
  const float* lnb = (const float*)d_in[4];
  float* out = (float*)d_out;

  float* X0  = (float*)d_ws;                 // [24000][1536]
  float* G0  = X0 + (size_t)GM * NG3;        // [16][1536]
  float* G1  = G0 + BB * NG3;                // [16][2048]
  float* Hb0 = G1 + BB * 2048;               // [8][16][512]
  float* Hb1 = Hb0 + 8 * BB * 512;           // [2][16][512]
  unsigned* tags = (unsigned*)(Hb1 + 2 * BB * 512);  // 336 flag lines

  hipMemsetAsync(tags, 0, 336 * FL * sizeof(unsigned), stream);

  dim3 ggrid(GM / 64, NG3 / 64);
  gemm_nt<<<ggrid, 256, 0, stream>>>(x, Wi, X0);  // layer-0 input gates
  gru_fused<<<2 * NCW + 32, 256, 0, stream>>>(
      Wh, Wi + (size_t)NG3 * 512, Wh + (size_t)NG3 * 512, X0, lnw, lnb, out,
      G0, G1, Hb0, Hb1, tags);
}